// Round 7
// baseline (2915.403 us; speedup 1.0000x reference)
//
#include <hip/hip_runtime.h>

#define HD 256
#define ID 32
#define OD 10
#define SEQ 512
#define NBG 16
#define HX_OFF 589824               // hx right after 576 KB packed weights
#define SMEM_BYTES (8192 + 65536)   // hbuf[2][16][128] + 8 waves x 8 LDS frags

typedef __attribute__((ext_vector_type(4))) float f32x4;
typedef __attribute__((ext_vector_type(4))) unsigned int u32x4;
typedef __attribute__((ext_vector_type(8))) unsigned short u16x8;
typedef __attribute__((ext_vector_type(8))) __bf16 bf16x8;

static __device__ __forceinline__ unsigned short f2bf(float f) {
  unsigned u = __builtin_bit_cast(unsigned, f);
  u += 0x7fffu + ((u >> 16) & 1u);          // RNE
  return (unsigned short)(u >> 16);
}
static __device__ __forceinline__ float bf2f(unsigned short s) {
  unsigned u = ((unsigned)s) << 16;
  return __builtin_bit_cast(float, u);
}
static __device__ __forceinline__ f32x4 mfma16(u16x8 a, u16x8 b, f32x4 c) {
  return __builtin_amdgcn_mfma_f32_16x16x32_bf16(
      __builtin_bit_cast(bf16x8, a), __builtin_bit_cast(bf16x8, b), c, 0, 0, 0);
}
static __device__ __forceinline__ float fast_sigmoid(float x) {
  return 1.f / (1.f + __expf(-x));
}
static __device__ __forceinline__ float fast_tanh(float x) {
  return 1.f - 2.f / (__expf(2.f * x) + 1.f);
}

// 8 x 16B device-coherent loads (no wait) — partner stamped words.
static __device__ __forceinline__ void issue8(const void* pa,
    u32x4& w0, u32x4& w1, u32x4& w2, u32x4& w3,
    u32x4& w4, u32x4& w5, u32x4& w6, u32x4& w7) {
  asm volatile(
      "global_load_dwordx4 %0, %8, off sc0 sc1\n\t"
      "global_load_dwordx4 %1, %8, off offset:16 sc0 sc1\n\t"
      "global_load_dwordx4 %2, %8, off offset:128 sc0 sc1\n\t"
      "global_load_dwordx4 %3, %8, off offset:144 sc0 sc1\n\t"
      "global_load_dwordx4 %4, %8, off offset:256 sc0 sc1\n\t"
      "global_load_dwordx4 %5, %8, off offset:272 sc0 sc1\n\t"
      "global_load_dwordx4 %6, %8, off offset:384 sc0 sc1\n\t"
      "global_load_dwordx4 %7, %8, off offset:400 sc0 sc1"
      : "=&v"(w0), "=&v"(w1), "=&v"(w2), "=&v"(w3),
        "=&v"(w4), "=&v"(w5), "=&v"(w6), "=&v"(w7)
      : "v"(pa)
      : "memory");
}
// Tie the loaded regs through a vmcnt wait so uses cannot be hoisted (rule #18).
static __device__ __forceinline__ void awaitv(
    u32x4& w0, u32x4& w1, u32x4& w2, u32x4& w3,
    u32x4& w4, u32x4& w5, u32x4& w6, u32x4& w7) {
  asm volatile("s_waitcnt vmcnt(0)"
      : "+v"(w0), "+v"(w1), "+v"(w2), "+v"(w3),
        "+v"(w4), "+v"(w5), "+v"(w6), "+v"(w7)
      :: "memory");
}

// ---------------------------------------------------------------------------
// Pack weights fragment-major (round-4 geometry, unchanged).
// hw = hf*8 + w (0..15), frag id f = hw*36 + g*9 + kt.
// lane l slot i -> W[k = 32kt + 8*(l>>4) + i][unit U = hw*16 + (l&15)] (gate g)
// ---------------------------------------------------------------------------
__global__ void pack_w(const float* __restrict__ Wgx, const float* __restrict__ Wgh,
                       const float* __restrict__ Wix, const float* __restrict__ Wih,
                       const float* __restrict__ Wfx, const float* __restrict__ Wfh,
                       const float* __restrict__ Wox, const float* __restrict__ Woh,
                       unsigned short* __restrict__ Wpk) {
  int p = blockIdx.x * blockDim.x + threadIdx.x;
  if (p >= 576 * 64) return;
  int f = p >> 6, l = p & 63;
  int hw = f / 36, r = f % 36;
  int g = r / 9, kt = r % 9;
  int U = hw * 16 + (l & 15);
  const float* Wx[4] = {Wgx, Wix, Wfx, Wox};
  const float* Wh[4] = {Wgh, Wih, Wfh, Woh};
  u16x8 v;
  #pragma unroll
  for (int i = 0; i < 8; ++i) {
    int k = kt * 32 + 8 * (l >> 4) + i;
    float val = (k < ID) ? Wx[g][k * HD + U] : Wh[g][(k - ID) * HD + U];
    v[i] = f2bf(val);
  }
  *(u16x8*)(Wpk + ((size_t)f << 9) + (l << 3)) = v;
}

template <int HF>
static __device__ __forceinline__ void mfma_own(
    const u16x8 (&wf)[4][7], const unsigned short* wlds_w, int l,
    const u16x8& ax, const u16x8 (&aown)[4], f32x4 (&acc)[4], bool full) {
  #pragma unroll
  for (int g = 0; g < 4; ++g) acc[g] = mfma16(ax, wf[g][0], acc[g]);
  if (!full) return;
  #pragma unroll
  for (int k2 = 0; k2 < 4; ++k2) {
    const int kt = 1 + 4 * HF + k2;
    #pragma unroll
    for (int g = 0; g < 4; ++g) {
      u16x8 bw;
      if (kt <= 6) bw = wf[g][kt];
      else bw = *(const u16x8*)(wlds_w + (g * 2 + (kt - 7)) * 512 + l * 8);
      acc[g] = mfma16(aown[k2], bw, acc[g]);
    }
  }
}
template <int HF>
static __device__ __forceinline__ void mfma_part(
    const u16x8 (&wf)[4][7], const unsigned short* wlds_w, int l,
    const u16x8 (&apart)[4], f32x4 (&acc)[4]) {
  #pragma unroll
  for (int k2 = 0; k2 < 4; ++k2) {
    const int kt = 1 + 4 * (1 - HF) + k2;
    #pragma unroll
    for (int g = 0; g < 4; ++g) {
      u16x8 bw;
      if (kt <= 6) bw = wf[g][kt];
      else bw = *(const u16x8*)(wlds_w + (g * 2 + (kt - 7)) * 512 + l * 8);
      acc[g] = mfma16(apart[k2], bw, acc[g]);
    }
  }
}

// ---------------------------------------------------------------------------
// 32 WGs = 16 batch-groups x 2 hidden-halves; 512 threads (8 waves).
// Weights resident (28 VGPR/AGPR + 8 LDS frags per wave).
// Exchange: flag-free. Each published word = (bf16<<16)|stamp(t+1), stored
// relaxed-agent (sc1); consumer loads sc0/sc1 dwordx4, validates stamps,
// retries if stale. Parity double-buffer (partner lead <= 1 step).
// One lgkmcnt-only raw barrier per step; no fences, no wbl2/inv.
// ---------------------------------------------------------------------------
__global__ void __launch_bounds__(512, 2) lstm_rec(
    const float* __restrict__ x, const unsigned short* __restrict__ Wpk,
    const float* __restrict__ bgp, const float* __restrict__ bip,
    const float* __restrict__ bfp, const float* __restrict__ bop,
    const float* __restrict__ Wph, const float* __restrict__ bpp,
    void* __restrict__ hx, float* __restrict__ out) {
  extern __shared__ __align__(16) char smem[];
  unsigned short* hbuf = (unsigned short*)smem;            // [2][16][128] bf16
  unsigned short* wlds = (unsigned short*)(smem + 8192);   // [8][8*512]

  const int tid = threadIdx.x;
  const int w = tid >> 6, l = tid & 63;
  const int l15 = l & 15, l4 = l >> 4;
  const int bgi = blockIdx.x & 15, hf = blockIdx.x >> 4;
  const int b0 = bgi * 16;
  char* hxc = (char*)hx;

  const unsigned short* wbase =
      Wpk + (((size_t)(hf * 8 + w) * 36) << 9) + (l << 3);
  unsigned short* wlds_w = wlds + w * 4096;

  // stage kt7,8 frags to LDS
  #pragma unroll
  for (int g = 0; g < 4; ++g)
    #pragma unroll
    for (int d = 0; d < 2; ++d) {
      u16x8 v = *(const u16x8*)(wbase + ((size_t)(g * 9 + 7 + d) << 9));
      *(u16x8*)(wlds_w + (g * 2 + d) * 512 + l * 8) = v;
    }
  // resident frags kt 0..6 (VGPR+AGPR)
  u16x8 wf[4][7];
  #pragma unroll
  for (int g = 0; g < 4; ++g)
    #pragma unroll
    for (int kt = 0; kt < 7; ++kt)
      wf[g][kt] = *(const u16x8*)(wbase + ((size_t)(g * 9 + kt) << 9));

  float bias[4];
  {
    const float* bs[4] = {bgp, bip, bfp, bop};
    #pragma unroll
    for (int g = 0; g < 4; ++g) bias[g] = bs[g][hf * 128 + w * 16 + l15];
  }
  float cst[4] = {0.f, 0.f, 0.f, 0.f};

  const float* xrow = x + ((size_t)(b0 + l15) * SEQ) * ID + 8 * l4;
  float4 xv0 = *(const float4*)xrow;
  float4 xv1 = *(const float4*)(xrow + 4);

  __syncthreads();

  #pragma unroll 1
  for (int t = 0; t < SEQ; ++t) {
    u16x8 ax;
    ax[0] = f2bf(xv0.x); ax[1] = f2bf(xv0.y); ax[2] = f2bf(xv0.z); ax[3] = f2bf(xv0.w);
    ax[4] = f2bf(xv1.x); ax[5] = f2bf(xv1.y); ax[6] = f2bf(xv1.z); ax[7] = f2bf(xv1.w);
    {
      int tn = (t + 1 < SEQ) ? (t + 1) : t;
      xv0 = *(const float4*)(xrow + (size_t)tn * ID);
      xv1 = *(const float4*)(xrow + (size_t)tn * ID + 4);
    }

    u16x8 aown[4];
    u32x4 w0, w1, w2, w3, w4, w5, w6, w7;
    const char* pa = hxc +
        ((((size_t)((t - 1) & 1)) * NBG + bgi) * 2 + (1 - hf)) * 8192 +
        l15 * 512 + l4 * 32;
    if (t > 0) {
      issue8(pa, w0, w1, w2, w3, w4, w5, w6, w7);   // partner loads in flight
      const unsigned short* hb = hbuf + ((t - 1) & 1) * 2048 + l15 * 128;
      #pragma unroll
      for (int k2 = 0; k2 < 4; ++k2) {
        int c = 4 * k2 + l4;
        aown[k2] = *(const u16x8*)(hb + ((c ^ l15) & 15) * 8);
      }
    }

    f32x4 acc[4];
    #pragma unroll
    for (int g = 0; g < 4; ++g)
      acc[g] = f32x4{bias[g], bias[g], bias[g], bias[g]};
    if (hf == 0) mfma_own<0>(wf, wlds_w, l, ax, aown, acc, t > 0);
    else         mfma_own<1>(wf, wlds_w, l, ax, aown, acc, t > 0);

    if (t > 0) {
      awaitv(w0, w1, w2, w3, w4, w5, w6, w7);
      const unsigned st = (unsigned)t;
      #define CK(W) (((W.x ^ st) & 0xffffu) | ((W.y ^ st) & 0xffffu) | \
                     ((W.z ^ st) & 0xffffu) | ((W.w ^ st) & 0xffffu))
      unsigned bad = CK(w0) | CK(w1) | CK(w2) | CK(w3) |
                     CK(w4) | CK(w5) | CK(w6) | CK(w7);
      while (!__all(bad == 0)) {                    // rare: partner not landed
        __builtin_amdgcn_s_sleep(1);
        issue8(pa, w0, w1, w2, w3, w4, w5, w6, w7);
        awaitv(w0, w1, w2, w3, w4, w5, w6, w7);
        bad = CK(w0) | CK(w1) | CK(w2) | CK(w3) |
              CK(w4) | CK(w5) | CK(w6) | CK(w7);
      }
      #undef CK
      u16x8 apart[4];
      #define UNP(k2, A, B) { u32x4 d_;                       \
        d_.x = (A.x >> 16) | (A.y & 0xffff0000u);             \
        d_.y = (A.z >> 16) | (A.w & 0xffff0000u);             \
        d_.z = (B.x >> 16) | (B.y & 0xffff0000u);             \
        d_.w = (B.z >> 16) | (B.w & 0xffff0000u);             \
        apart[k2] = __builtin_bit_cast(u16x8, d_); }
      UNP(0, w0, w1) UNP(1, w2, w3) UNP(2, w4, w5) UNP(3, w6, w7)
      #undef UNP
      if (hf == 0) mfma_part<0>(wf, wlds_w, l, apart, acc);
      else         mfma_part<1>(wf, wlds_w, l, apart, acc);
    }

    // gates; D layout: col(unit)=l15, row(batch)=4*l4+i
    unsigned short* ho = hbuf + (t & 1) * 2048;
    unsigned int* hxw = (unsigned int*)(hxc +
        ((((size_t)(t & 1)) * NBG + bgi) * 2 + hf) * 8192);
    const unsigned stp = (unsigned)(t + 1);
    int ul = 16 * w + l15;
    #pragma unroll
    for (int i = 0; i < 4; ++i) {
      float gg = fast_tanh(acc[0][i]);
      float ii = fast_sigmoid(acc[1][i]);
      float ff = fast_sigmoid(acc[2][i]);
      float oo = fast_sigmoid(acc[3][i]);
      float cc = gg * ii + cst[i] * ff;
      cst[i] = cc;
      float hh = fast_tanh(cc) * oo;
      unsigned short me = f2bf(hh);
      int r = 4 * l4 + i;
      ho[r * 128 + (((ul >> 3) ^ r) & 15) * 8 + (ul & 7)] = me;
      __hip_atomic_store(hxw + r * 128 + ul, ((unsigned)me << 16) | stp,
                         __ATOMIC_RELAXED, __HIP_MEMORY_SCOPE_AGENT);
    }
    // raw barrier: drain LDS only; publish stores stay in flight.
    __builtin_amdgcn_sched_barrier(0);
    asm volatile("s_waitcnt lgkmcnt(0)" ::: "memory");
    __builtin_amdgcn_s_barrier();
    __builtin_amdgcn_sched_barrier(0);
  }

  // ---- epilogue: half-0 fetches partner h_511 (stamp 512), logits+softmax --
  if (hf == 0) {
    unsigned short* hfin = (unsigned short*)(smem + 8192);  // [16][256]
    // own half from swizzled LDS parity 1
    for (int idx = tid; idx < 2048; idx += 512) {
      int row = idx >> 7, uo = idx & 127;
      hfin[row * 256 + uo] =
          hbuf[2048 + row * 128 + (((uo >> 3) ^ row) & 15) * 8 + (uo & 7)];
    }
    // partner half: 4 stamped words per thread
    {
      const char* pe = hxc + (((size_t)1 * NBG + bgi) * 2 + 1) * 8192 + tid * 16;
      u32x4 e;
      for (;;) {
        asm volatile(
            "global_load_dwordx4 %0, %1, off sc0 sc1\n\t"
            "s_waitcnt vmcnt(0)"
            : "=&v"(e) : "v"(pe) : "memory");
        unsigned bad = ((e.x ^ 512u) & 0xffffu) | ((e.y ^ 512u) & 0xffffu) |
                       ((e.z ^ 512u) & 0xffffu) | ((e.w ^ 512u) & 0xffffu);
        if (__all(bad == 0)) break;
        __builtin_amdgcn_s_sleep(1);
      }
      int row = tid >> 5, ul0 = (tid & 31) * 4;
      hfin[row * 256 + 128 + ul0 + 0] = (unsigned short)(e.x >> 16);
      hfin[row * 256 + 128 + ul0 + 1] = (unsigned short)(e.y >> 16);
      hfin[row * 256 + 128 + ul0 + 2] = (unsigned short)(e.z >> 16);
      hfin[row * 256 + 128 + ul0 + 3] = (unsigned short)(e.w >> 16);
    }
    __syncthreads();
    float* lbuf = (float*)(smem + 8192 + 16384);
    if (tid < 16 * OD) {
      int eb = tid & 15, ej = tid >> 4;
      float s = bpp[ej];
      for (int k = 0; k < HD; ++k)
        s += bf2f(hfin[eb * 256 + k]) * Wph[k * OD + ej];
      lbuf[eb * OD + ej] = s;
    }
    __syncthreads();
    if (tid < 16) {
      float m = -1e30f;
      #pragma unroll
      for (int j = 0; j < OD; ++j) m = fmaxf(m, lbuf[tid * OD + j]);
      float e[OD], sum = 0.f;
      #pragma unroll
      for (int j = 0; j < OD; ++j) { e[j] = __expf(lbuf[tid * OD + j] - m); sum += e[j]; }
      float inv = 1.f / sum;
      #pragma unroll
      for (int j = 0; j < OD; ++j) out[(b0 + tid) * OD + j] = e[j] * inv;
    }
  }
}

extern "C" void kernel_launch(void* const* d_in, const int* in_sizes, int n_in,
                              void* d_out, int out_size, void* d_ws, size_t ws_size,
                              hipStream_t stream) {
  const float* X   = (const float*)d_in[0];
  const float* Wgx = (const float*)d_in[1];
  const float* Wgh = (const float*)d_in[2];
  const float* bg  = (const float*)d_in[3];
  const float* Wix = (const float*)d_in[4];
  const float* Wih = (const float*)d_in[5];
  const float* bi  = (const float*)d_in[6];
  const float* Wfx = (const float*)d_in[7];
  const float* Wfh = (const float*)d_in[8];
  const float* bf  = (const float*)d_in[9];
  const float* Wox = (const float*)d_in[10];
  const float* Woh = (const float*)d_in[11];
  const float* bo  = (const float*)d_in[12];
  const float* Wph = (const float*)d_in[13];
  const float* bp  = (const float*)d_in[14];

  unsigned short* Wpk = (unsigned short*)d_ws;        // 576 KB packed weights
  void*           hx  = (char*)d_ws + HX_OFF;         // 512 KB stamped h x-change

  hipMemsetAsync((char*)d_ws + HX_OFF, 0, 2 * NBG * 2 * 8192, stream);
  (void)hipFuncSetAttribute((const void*)lstm_rec,
                            hipFuncAttributeMaxDynamicSharedMemorySize,
                            SMEM_BYTES);

  pack_w<<<dim3(72), dim3(512), 0, stream>>>(Wgx, Wgh, Wix, Wih, Wfx, Wfh,
                                             Wox, Woh, Wpk);
  lstm_rec<<<dim3(32), dim3(512), SMEM_BYTES, stream>>>(
      X, Wpk, bg, bi, bf, bo, Wph, bp, hx, (float*)d_out);
}